// Round 9
// baseline (156.468 us; speedup 1.0000x reference)
//
#include <hip/hip_runtime.h>

typedef _Float16 half_t;
typedef _Float16 h8 __attribute__((ext_vector_type(8)));
typedef _Float16 h4 __attribute__((ext_vector_type(4)));
typedef _Float16 h2 __attribute__((ext_vector_type(2)));
typedef float f32x4 __attribute__((ext_vector_type(4)));
typedef float f32x16 __attribute__((ext_vector_type(16)));

#define S_LEN 2048
#define DMODEL 1024
#define NHEAD 16
#define HDK 64
#define NB 2
#define LOG2E 1.44269504089f

// ---------------------------------------------------------------------------
__device__ __forceinline__ void gload_lds16(const void* g, void* l) {
  __builtin_amdgcn_global_load_lds(
      (const __attribute__((address_space(1))) unsigned int*)g,
      (__attribute__((address_space(3))) unsigned int*)l, 16, 0, 0);
}

__device__ __forceinline__ float fast_exp2(float x) {
  float r;
  asm("v_exp_f32 %0, %1" : "=v"(r) : "v"(x));
  return r;
}

// XOR swizzle for 128-byte LDS rows (attn tiles)
__device__ __forceinline__ int swz(int row, int colByte) {
  return row * 128 + (colByte ^ ((row & 7) << 4));
}

// ---------------------------------------------------------------------------
// Fused prologue: f32->f16 converts + mask bit-pack into TRANSPOSED layout
// mbT[word][qrow] (word = k>>5) so attn's per-tile mask read is coalesced.
__global__ __launch_bounds__(256) void pre_kernel(
    const float* __restrict__ q, const float* __restrict__ k, const float* __restrict__ v,
    const float* __restrict__ wq, const float* __restrict__ wk,
    const float* __restrict__ wv, const float* __restrict__ wo,
    const int* __restrict__ mask,
    half_t* Xq, half_t* Xk, half_t* Xv,
    half_t* Wq, half_t* Wk, half_t* Wv, half_t* Wo,
    unsigned int* mbT) {
  const int gid = blockIdx.x, tid = threadIdx.x;
  if (gid < 16384) {
    int i = gid * 256 + tid;
    const float* src; half_t* dst; int off;
    if (i < 3145728) {
      int rgn = i >> 20; off = i & 1048575;
      src = rgn == 0 ? q : rgn == 1 ? k : v;
      dst = rgn == 0 ? Xq : rgn == 1 ? Xk : Xv;
    } else {
      int j = i - 3145728;
      int rgn = j >> 18; off = j & 262143;
      src = rgn == 0 ? wq : rgn == 1 ? wk : rgn == 2 ? wv : wo;
      dst = rgn == 0 ? Wq : rgn == 1 ? Wk : rgn == 2 ? Wv : Wo;
    }
    float4 vv = ((const float4*)src)[off];
    h4 o;
    o[0] = (half_t)vv.x; o[1] = (half_t)vv.y; o[2] = (half_t)vv.z; o[3] = (half_t)vv.w;
    ((h4*)dst)[off] = o;
  } else {
    int i = (gid - 16384) * 256 + tid;  // i = qrow*2048 + kcol
    int mv = mask[i];
    unsigned long long bm = __ballot(mv != 0);
    int lane = tid & 63;
    int widx = ((i >> 5) & 63);   // k chunk
    int qrow = i >> 11;
    if (lane == 0)       mbT[widx * S_LEN + qrow] = (unsigned int)bm;
    else if (lane == 32) mbT[widx * S_LEN + qrow] = (unsigned int)(bm >> 32);
  }
}

// ---------------------------------------------------------------------------
// NT GEMM, m97/BK=32 fragment math (R7-validated) + T3/T4 deep pipeline:
// 4 rotating LDS buffers, prefetch distance 2, counted s_waitcnt vmcnt(8),
// raw s_barrier (no full drain), unroll-4 for static buffer indices.
template <int EPI>
__global__ __launch_bounds__(256, 2) void gemm_kernel(
    const half_t* __restrict__ A0, const half_t* __restrict__ A1, const half_t* __restrict__ A2,
    const half_t* __restrict__ W0, const half_t* __restrict__ W1, const half_t* __restrict__ W2,
    const float* __restrict__ b0, const float* __restrict__ b1, const float* __restrict__ b2,
    void* o0, void* o1, void* o2) {
  const int nwg = gridDim.x;
  const int cpx = nwg >> 3;
  const int id = blockIdx.x;
  const int nid = (id & 7) * cpx + (id >> 3);
  const int z = nid >> 8;
  const int rmn = nid & 255;
  const int bm = rmn >> 3, bn = rmn & 7;

  const half_t* A; const half_t* W; const float* bias; void* out; float scale;
  if (z == 0)      { A = A0; W = W0; bias = b0; out = o0; scale = (EPI == 0) ? 0.125f * LOG2E : 1.0f; }
  else if (z == 1) { A = A1; W = W1; bias = b1; out = o1; scale = 1.0f; }
  else             { A = A2; W = W2; bias = b2; out = o2; scale = 1.0f; }

  __shared__ half_t As[4][128 * 32];
  __shared__ half_t Bs[4][128 * 32];
  const int tid = threadIdx.x;
  const int w = tid >> 6, lane = tid & 63;
  const int wm = w >> 1, wn = w & 1;
  const int crow = lane >> 2;
  const int ckb = ((lane & 3) * 16) ^ ((crow & 3) << 4);  // pre-swizzled src col

  f32x4 acc[4][4] = {};

  const char* Ar0 = (const char*)A + (size_t)(bm * 128 + w * 16 + crow) * 2048 + ckb;
  const char* Ar1 = Ar0 + 64 * 2048;
  const char* Wr0 = (const char*)W + (size_t)(bn * 128 + w * 16 + crow) * 2048 + ckb;
  const char* Wr1 = Wr0 + 64 * 2048;

  const int rr = lane & 15;
  const int kkB = (lane >> 4) * 16;
  const int kswz = (rr & 3) << 4;

#define GS(BUF, T)                                          \
  { const int ktB_ = (T) * 64;                              \
    gload_lds16(Ar0 + ktB_, As[BUF] + w * 512);             \
    gload_lds16(Ar1 + ktB_, As[BUF] + (w + 4) * 512);       \
    gload_lds16(Wr0 + ktB_, Bs[BUF] + w * 512);             \
    gload_lds16(Wr1 + ktB_, Bs[BUF] + (w + 4) * 512); }

#define GW                                                  \
  asm volatile("s_waitcnt vmcnt(8)" ::: "memory");          \
  __builtin_amdgcn_sched_barrier(0);                        \
  __builtin_amdgcn_s_barrier();                             \
  __builtin_amdgcn_sched_barrier(0);

#define GC(BUF)                                                          \
  { const char* AsB = (const char*)As[BUF];                              \
    const char* BsB = (const char*)Bs[BUF];                              \
    h8 af[4], bf[4];                                                     \
    _Pragma("unroll") for (int i_ = 0; i_ < 4; ++i_) {                   \
      af[i_] = *(const h8*)(AsB + (wm * 64 + i_ * 16 + rr) * 64 + (kkB ^ kswz)); \
      bf[i_] = *(const h8*)(BsB + (wn * 64 + i_ * 16 + rr) * 64 + (kkB ^ kswz)); \
    }                                                                    \
    __builtin_amdgcn_s_setprio(1);                                       \
    _Pragma("unroll") for (int i_ = 0; i_ < 4; ++i_)                     \
      _Pragma("unroll") for (int j_ = 0; j_ < 4; ++j_)                   \
        acc[i_][j_] = __builtin_amdgcn_mfma_f32_16x16x32_f16(af[i_], bf[j_], acc[i_][j_], 0, 0, 0); \
    __builtin_amdgcn_s_setprio(0); }

  GS(0, 0); GS(1, 1);
  for (int g = 0; g < 8; ++g) {
    const int i0 = g * 4;
    GS(2, i0 + 2); GW; GC(0);
    GS(3, i0 + 3); GW; GC(1);
    { int t2 = i0 + 4; if (t2 > 31) t2 = 31; GS(0, t2); } GW; GC(2);
    { int t2 = i0 + 5; if (t2 > 31) t2 = 31; GS(1, t2); } GW; GC(3);
  }
#undef GS
#undef GW
#undef GC

  const int r0 = bm * 128 + wm * 64;
  const int c0 = bn * 128 + wn * 64;
#pragma unroll
  for (int j = 0; j < 4; ++j) {
    int col = c0 + j * 16 + (lane & 15);
    float bc = bias[col];
#pragma unroll
    for (int i = 0; i < 4; ++i) {
#pragma unroll
      for (int jj = 0; jj < 4; ++jj) {
        int row = r0 + i * 16 + (lane >> 4) * 4 + jj;
        float val = acc[i][j][jj] + bc;
        if (EPI == 0) {
          int bb = row >> 11, s = row & (S_LEN - 1);
          int hh = col >> 6, dk = col & 63;
          if (z == 2) {  // V^T: [B,H,64,S]
            ((half_t*)out)[((size_t)((bb * NHEAD + hh) * HDK + dk)) * S_LEN + s] = (half_t)val;
          } else {
            ((half_t*)out)[(((size_t)(bb * NHEAD + hh)) * S_LEN + s) * HDK + dk] =
                (half_t)(val * scale);
          }
        } else {
          ((float*)out)[(size_t)row * DMODEL + col] = val;
        }
      }
    }
  }
}

// ---------------------------------------------------------------------------
// Flash attention v7 = v6 compute (validated) + T3/T4 deep pipeline:
// 4 rotating K/V buffers (64 KB), prefetch distance 2, counted vmcnt(10)
// (4 stage + 1 mask load per iter), raw s_barrier, unroll-4 (static buffer
// and mask-slot indices). Mask reads now coalesced (transposed mbT layout).
__global__ __launch_bounds__(256, 2) void attn_kernel(
    const half_t* __restrict__ Qp, const half_t* __restrict__ Kp,
    const half_t* __restrict__ VTp, const unsigned int* __restrict__ mbT,
    half_t* __restrict__ AO) {
  __shared__ char smem[65536];  // Ks[4][8192] | Vs[4][8192]; merge reuse

  const int tid = threadIdx.x, w = tid >> 6, lane = tid & 63;
  const int qg = w >> 1, kh = w & 1;
  const int id = blockIdx.x;
  const int xcd = id & 7, rest = id >> 3;
  const int bh = (xcd << 2) | (rest >> 5);
  const int qt = rest & 31;
  const int b = bh >> 4, h = bh & 15;
  const int q32 = lane & 31, hi = lane >> 5;
  const int qbase = qt * 64 + qg * 32;
  const half_t* Qb = Qp + (size_t)bh * (S_LEN * HDK);
  const char* Kb = (const char*)(Kp + (size_t)bh * (S_LEN * HDK));
  const char* VTb = (const char*)(VTp + (size_t)bh * (S_LEN * HDK));

  char* Ks = smem;           // [4][8192]
  char* Vs = smem + 32768;   // [4][8192]
  const int srow = w * 16 + (lane >> 3);
  const int scb = (lane & 7) * 16;

  h8 qf[4];
#pragma unroll
  for (int s = 0; s < 4; ++s)
    qf[s] = *(const h8*)(Qb + (size_t)(qbase + q32) * HDK + s * 16 + hi * 8);

  f32x16 acc0 = {}, acc1 = {};
  float l_run = 0.f;
  unsigned int mw0s, mw1s, mw2s, mw3s;

#define ASTG(BUF, T)                                                        \
  { const int t_ = (T);                                                     \
    _Pragma("unroll") for (int p = 0; p < 2; ++p) {                         \
      int r = srow + p * 8;                                                 \
      gload_lds16(Kb + (size_t)(t_ * 64 + r) * 128 + (scb ^ ((r & 7) << 4)),\
                  Ks + (BUF) * 8192 + (w * 16 + p * 8) * 128);              \
      gload_lds16(VTb + (size_t)r * (S_LEN * 2) + t_ * 128 + (scb ^ ((r & 7) << 4)), \
                  Vs + (BUF) * 8192 + (w * 16 + p * 8) * 128);              \
    } }

#define AMSK(VAR, T) VAR = mbT[(size_t)((T) * 2 + kh) * S_LEN + qbase + q32];

#define AW                                                  \
  asm volatile("s_waitcnt vmcnt(10)" ::: "memory");         \
  __builtin_amdgcn_sched_barrier(0);                        \
  __builtin_amdgcn_s_barrier();                             \
  __builtin_amdgcn_sched_barrier(0);

#define ABODY(BUF, MW)                                                      \
  { const char* kb = Ks + (BUF) * 8192;                                     \
    const char* vb = Vs + (BUF) * 8192;                                     \
    const unsigned int mwc = (MW) >> (hi * 4);                              \
    f32x16 sc = {};                                                         \
    __builtin_amdgcn_s_setprio(1);                                          \
    _Pragma("unroll") for (int s = 0; s < 4; ++s) {                         \
      h8 kf = *(const h8*)(kb + swz(kh * 32 + q32, s * 32 + hi * 16));      \
      sc = __builtin_amdgcn_mfma_f32_32x32x16_f16(kf, qf[s], sc, 0, 0, 0);  \
    }                                                                       \
    __builtin_amdgcn_s_setprio(0);                                          \
    h8 vf00 = *(const h8*)(vb + swz(q32, kh * 64 + hi * 16));               \
    h8 vf01 = *(const h8*)(vb + swz(q32, kh * 64 + 32 + hi * 16));          \
    h8 vf10 = *(const h8*)(vb + swz(32 + q32, kh * 64 + hi * 16));          \
    h8 vf11 = *(const h8*)(vb + swz(32 + q32, kh * 64 + 32 + hi * 16));     \
    _Pragma("unroll") for (int rg = 0; rg < 16; ++rg) {                     \
      const int bit = (rg & 3) + 8 * (rg >> 2);                             \
      float p = fast_exp2(((mwc >> bit) & 1u) ? sc[rg] : 0.0f);             \
      sc[rg] = p;                                                           \
      l_run += p;                                                           \
    }                                                                       \
    h8 pb[2];                                                               \
    _Pragma("unroll") for (int s = 0; s < 2; ++s) {                         \
      const int rb = s * 8;                                                 \
      union { h2 h_; unsigned int u; } c01, c23, c45, c67;                  \
      c01.h_[0] = (half_t)sc[rb + 0]; c01.h_[1] = (half_t)sc[rb + 1];       \
      c23.h_[0] = (half_t)sc[rb + 2]; c23.h_[1] = (half_t)sc[rb + 3];       \
      c45.h_[0] = (half_t)sc[rb + 4]; c45.h_[1] = (half_t)sc[rb + 5];       \
      c67.h_[0] = (half_t)sc[rb + 6]; c67.h_[1] = (half_t)sc[rb + 7];       \
      auto rA = __builtin_amdgcn_permlane32_swap(c01.u, c45.u, false, false);\
      auto rB = __builtin_amdgcn_permlane32_swap(c23.u, c67.u, false, false);\
      union { unsigned int u[4]; h8 v_; } bw;                               \
      bw.u[0] = rA[0]; bw.u[1] = rB[0]; bw.u[2] = rA[1]; bw.u[3] = rB[1];   \
      pb[s] = bw.v_;                                                        \
    }                                                                       \
    __builtin_amdgcn_s_setprio(1);                                          \
    acc0 = __builtin_amdgcn_mfma_f32_32x32x16_f16(vf00, pb[0], acc0, 0, 0, 0); \
    acc1 = __builtin_amdgcn_mfma_f32_32x32x16_f16(vf10, pb[0], acc1, 0, 0, 0); \
    acc0 = __builtin_amdgcn_mfma_f32_32x32x16_f16(vf01, pb[1], acc0, 0, 0, 0); \
    acc1 = __builtin_amdgcn_mfma_f32_32x32x16_f16(vf11, pb[1], acc1, 0, 0, 0); \
    __builtin_amdgcn_s_setprio(0); }

  ASTG(0, 0); AMSK(mw0s, 0);
  ASTG(1, 1); AMSK(mw1s, 1);
  for (int g = 0; g < 8; ++g) {
    const int i0 = g * 4;
    ASTG(2, i0 + 2); AMSK(mw2s, i0 + 2); AW; ABODY(0, mw0s);
    ASTG(3, i0 + 3); AMSK(mw3s, i0 + 3); AW; ABODY(1, mw1s);
    { int t2 = i0 + 4; if (t2 > 31) t2 = 31; ASTG(0, t2); AMSK(mw0s, t2); }
    AW; ABODY(2, mw2s);
    { int t2 = i0 + 5; if (t2 > 31) t2 = 31; ASTG(1, t2); AMSK(mw1s, t2); }
    AW; ABODY(3, mw3s);
  }
#undef ASTG
#undef AMSK
#undef AW
#undef ABODY

  // drain in-flight tail prefetches before reusing smem as the merge area
  __syncthreads();

  float* my = (float*)smem + (qg * 64 + lane) * 33;
  if (kh) {
#pragma unroll
    for (int rg = 0; rg < 16; ++rg) { my[rg] = acc0[rg]; my[16 + rg] = acc1[rg]; }
    my[32] = l_run;
  }
  __syncthreads();
  if (!kh) {
#pragma unroll
    for (int rg = 0; rg < 16; ++rg) { acc0[rg] += my[rg]; acc1[rg] += my[16 + rg]; }
    l_run += my[32];
    l_run += __shfl_xor(l_run, 32);

    const float inv = 1.0f / l_run;
    const int qrow = qbase + q32;
    half_t* aob = AO + (size_t)(b * S_LEN + qrow) * DMODEL + h * HDK;
#pragma unroll
    for (int rq = 0; rq < 4; ++rq) {
      h4 s0, s1;
#pragma unroll
      for (int j = 0; j < 4; ++j) {
        s0[j] = (half_t)(acc0[rq * 4 + j] * inv);
        s1[j] = (half_t)(acc1[rq * 4 + j] * inv);
      }
      const int d0 = 8 * rq + 4 * hi;
      *(h4*)(aob + d0) = s0;
      *(h4*)(aob + 32 + d0) = s1;
    }
  }
}

// ---------------------------------------------------------------------------
extern "C" void kernel_launch(void* const* d_in, const int* in_sizes, int n_in,
                              void* d_out, int out_size, void* d_ws, size_t ws_size,
                              hipStream_t stream) {
  const float* q    = (const float*)d_in[0];
  const float* k    = (const float*)d_in[1];
  const float* v    = (const float*)d_in[2];
  const int*   mask = (const int*)d_in[3];
  const float* wq_w = (const float*)d_in[4];
  const float* wq_b = (const float*)d_in[5];
  const float* wk_w = (const float*)d_in[6];
  const float* wk_b = (const float*)d_in[7];
  const float* wv_w = (const float*)d_in[8];
  const float* wv_b = (const float*)d_in[9];
  const float* wo_w = (const float*)d_in[10];
  const float* wo_b = (const float*)d_in[11];
  float* out = (float*)d_out;

  char* ws = (char*)d_ws;
  const size_t MB = (size_t)1 << 20;
  half_t* Xq = (half_t*)(ws + 0 * MB);
  half_t* Xk = (half_t*)(ws + 8 * MB);
  half_t* Xv = (half_t*)(ws + 16 * MB);
  half_t* Wq = (half_t*)(ws + 24 * MB);
  half_t* Wk = (half_t*)(ws + 26 * MB);
  half_t* Wv = (half_t*)(ws + 28 * MB);
  half_t* Wo = (half_t*)(ws + 30 * MB);
  half_t* Qp = (half_t*)(ws + 32 * MB);
  half_t* Kp = (half_t*)(ws + 40 * MB);
  half_t* VT = (half_t*)(ws + 48 * MB);
  unsigned int* mbT = (unsigned int*)(ws + 56 * MB);
  half_t* AO = Xq;  // Xq dead after projections

  pre_kernel<<<32768, 256, 0, stream>>>(q, k, v, wq_w, wk_w, wv_w, wo_w, mask,
                                        Xq, Xk, Xv, Wq, Wk, Wv, Wo, mbT);
  gemm_kernel<0><<<768, 256, 0, stream>>>(
      Xq, Xk, Xv, Wq, Wk, Wv, wq_b, wk_b, wv_b, (void*)Qp, (void*)Kp, (void*)VT);
  attn_kernel<<<1024, 256, 0, stream>>>(Qp, Kp, VT, mbT, AO);
  gemm_kernel<1><<<256, 256, 0, stream>>>(
      AO, AO, AO, Wo, Wo, Wo, wo_b, wo_b, wo_b, (void*)out, (void*)out, (void*)out);

  (void)in_sizes; (void)n_in; (void)out_size; (void)ws_size;
}

// Round 11
// 142.392 us; speedup vs baseline: 1.0989x; 1.0989x over previous
//
#include <hip/hip_runtime.h>

typedef _Float16 half_t;
typedef _Float16 h8 __attribute__((ext_vector_type(8)));
typedef _Float16 h4 __attribute__((ext_vector_type(4)));
typedef _Float16 h2 __attribute__((ext_vector_type(2)));
typedef __fp16 fp16x2 __attribute__((ext_vector_type(2)));
typedef float f32x4 __attribute__((ext_vector_type(4)));
typedef float f32x16 __attribute__((ext_vector_type(16)));

#define S_LEN 2048
#define DMODEL 1024
#define NHEAD 16
#define HDK 64
#define NB 2
#define LOG2E 1.44269504089f

// ---------------------------------------------------------------------------
__device__ __forceinline__ void gload_lds16(const void* g, void* l) {
  __builtin_amdgcn_global_load_lds(
      (const __attribute__((address_space(1))) unsigned int*)g,
      (__attribute__((address_space(3))) unsigned int*)l, 16, 0, 0);
}

__device__ __forceinline__ float fast_exp2(float x) {
  float r;
  asm("v_exp_f32 %0, %1" : "=v"(r) : "v"(x));
  return r;
}

// XOR swizzle for 128-byte LDS rows (attn tiles)
__device__ __forceinline__ int swz(int row, int colByte) {
  return row * 128 + (colByte ^ ((row & 7) << 4));
}

// ---------------------------------------------------------------------------
// Fused prologue: f32->f16 converts + mask bit-pack into TRANSPOSED layout
// mbT[word][qrow] (word = k>>5) so attn's per-tile mask read is coalesced.
__global__ __launch_bounds__(256) void pre_kernel(
    const float* __restrict__ q, const float* __restrict__ k, const float* __restrict__ v,
    const float* __restrict__ wq, const float* __restrict__ wk,
    const float* __restrict__ wv, const float* __restrict__ wo,
    const int* __restrict__ mask,
    half_t* Xq, half_t* Xk, half_t* Xv,
    half_t* Wq, half_t* Wk, half_t* Wv, half_t* Wo,
    unsigned int* mbT) {
  const int gid = blockIdx.x, tid = threadIdx.x;
  if (gid < 16384) {
    int i = gid * 256 + tid;
    const float* src; half_t* dst; int off;
    if (i < 3145728) {
      int rgn = i >> 20; off = i & 1048575;
      src = rgn == 0 ? q : rgn == 1 ? k : v;
      dst = rgn == 0 ? Xq : rgn == 1 ? Xk : Xv;
    } else {
      int j = i - 3145728;
      int rgn = j >> 18; off = j & 262143;
      src = rgn == 0 ? wq : rgn == 1 ? wk : rgn == 2 ? wv : wo;
      dst = rgn == 0 ? Wq : rgn == 1 ? Wk : rgn == 2 ? Wv : Wo;
    }
    float4 vv = ((const float4*)src)[off];
    h4 o;
    o[0] = (half_t)vv.x; o[1] = (half_t)vv.y; o[2] = (half_t)vv.z; o[3] = (half_t)vv.w;
    ((h4*)dst)[off] = o;
  } else {
    int i = (gid - 16384) * 256 + tid;  // i = qrow*2048 + kcol
    int mv = mask[i];
    unsigned long long bm = __ballot(mv != 0);
    int lane = tid & 63;
    int widx = ((i >> 5) & 63);
    int qrow = i >> 11;
    if (lane == 0)       mbT[widx * S_LEN + qrow] = (unsigned int)bm;
    else if (lane == 32) mbT[widx * S_LEN + qrow] = (unsigned int)(bm >> 32);
  }
}

// ---------------------------------------------------------------------------
// QKV projection GEMM (R7-validated compute): 128x128 tile, BK=32, 2-buf
// single-barrier, both-sides XOR swizzle, XCD-chunked flat grid.
// z=0 -> Q [B,H,S,64] * (1/8*log2e); z=1 -> K [B,H,S,64];
// z=2 -> V^T [B,H,64,S] via LDS-transpose epilogue (coalesced 128B stores).
__global__ __launch_bounds__(256) void gemm_kernel(
    const half_t* __restrict__ A0, const half_t* __restrict__ A1, const half_t* __restrict__ A2,
    const half_t* __restrict__ W0, const half_t* __restrict__ W1, const half_t* __restrict__ W2,
    const float* __restrict__ b0, const float* __restrict__ b1, const float* __restrict__ b2,
    void* o0, void* o1, void* o2) {
  const int nwg = gridDim.x;            // 768
  const int cpx = nwg >> 3;             // 96
  const int id = blockIdx.x;
  const int nid = (id & 7) * cpx + (id >> 3);
  const int z = nid >> 8;
  const int rmn = nid & 255;
  const int bm = rmn >> 3, bn = rmn & 7;

  const half_t* A; const half_t* W; const float* bias; void* out; float scale;
  if (z == 0)      { A = A0; W = W0; bias = b0; out = o0; scale = 0.125f * LOG2E; }
  else if (z == 1) { A = A1; W = W1; bias = b1; out = o1; scale = 1.0f; }
  else             { A = A2; W = W2; bias = b2; out = o2; scale = 1.0f; }

  __shared__ char gsm[32768];  // As[2][8KB] @0 | Bs[2][8KB] @16384; Ct reuse
#define ASB(buf) (gsm + (buf) * 8192)
#define BSB(buf) (gsm + 16384 + (buf) * 8192)

  const int tid = threadIdx.x;
  const int w = tid >> 6, lane = tid & 63;
  const int wm = w >> 1, wn = w & 1;
  const int crow = lane >> 2;
  const int ckb = ((lane & 3) * 16) ^ ((crow & 3) << 4);  // pre-swizzled src col

  f32x4 acc[4][4] = {};

  const char* Ar0 = (const char*)A + (size_t)(bm * 128 + w * 16 + crow) * 2048 + ckb;
  const char* Ar1 = Ar0 + 64 * 2048;
  const char* Wr0 = (const char*)W + (size_t)(bn * 128 + w * 16 + crow) * 2048 + ckb;
  const char* Wr1 = Wr0 + 64 * 2048;

  const int rr = lane & 15;
  const int kkB = (lane >> 4) * 16;
  const int kswz = (rr & 3) << 4;

#define GSTAGE(buf, ktB)                                     \
  do {                                                       \
    gload_lds16(Ar0 + (ktB), ASB(buf) + w * 1024);           \
    gload_lds16(Ar1 + (ktB), ASB(buf) + (w + 4) * 1024);     \
    gload_lds16(Wr0 + (ktB), BSB(buf) + w * 1024);           \
    gload_lds16(Wr1 + (ktB), BSB(buf) + (w + 4) * 1024);     \
  } while (0)

  GSTAGE(0, 0);
  __syncthreads();

  int cur = 0;
  for (int ktB = 0; ktB < 2048; ktB += 64) {
    if (ktB + 64 < 2048) GSTAGE(cur ^ 1, ktB + 64);

    const char* AsB = ASB(cur);
    const char* BsB = BSB(cur);
    h8 af[4], bf[4];
#pragma unroll
    for (int i = 0; i < 4; ++i) {
      af[i] = *(const h8*)(AsB + (wm * 64 + i * 16 + rr) * 64 + (kkB ^ kswz));
      bf[i] = *(const h8*)(BsB + (wn * 64 + i * 16 + rr) * 64 + (kkB ^ kswz));
    }
#pragma unroll
    for (int i = 0; i < 4; ++i)
#pragma unroll
      for (int j = 0; j < 4; ++j)
        acc[i][j] = __builtin_amdgcn_mfma_f32_16x16x32_f16(af[i], bf[j], acc[i][j], 0, 0, 0);

    __syncthreads();
    cur ^= 1;
  }
#undef GSTAGE

  const int c0 = bn * 128;
  if (z == 2) {
    // --- V^T LDS-transpose epilogue ---
    // Stage C-tile into Ct[col][row] (f16, 256B per col) with 16B-granular
    // XOR swizzle: byte(col,row) = col*256 + ((2*row) ^ ((col&15)<<4)).
    char* Ct = gsm;
    const int g4 = (lane >> 4) * 4;
#pragma unroll
    for (int j = 0; j < 4; ++j) {
      const int lcol = wn * 64 + j * 16 + rr;
      const float bc = bias[c0 + lcol];
      const int cswz = (lcol & 15) << 4;
      char* colp = Ct + lcol * 256;
#pragma unroll
      for (int i = 0; i < 4; ++i) {
#pragma unroll
        for (int jj = 0; jj < 4; jj += 2) {
          const int lrow = wm * 64 + i * 16 + g4 + jj;
          union { h2 hh; unsigned u; } t;
          t.hh[0] = (half_t)(acc[i][j][jj] + bc);
          t.hh[1] = (half_t)(acc[i][j][jj + 1] + bc);
          *(unsigned*)(colp + ((2 * lrow) ^ cswz)) = t.u;
        }
      }
    }
    __syncthreads();
    // read columns (b128, swizzled) and store coalesced 128B per thread
    const int col = tid >> 1, hf = tid & 1;
    const int bb = bm >> 4, s0 = (bm & 15) * 128;
    const int hh2 = (c0 + col) >> 6, dk = (c0 + col) & 63;
    half_t* dst = (half_t*)out +
        ((size_t)((bb * NHEAD + hh2) * HDK + dk)) * S_LEN + s0 + hf * 64;
    const int cswz = (col & 15) << 4;
    const char* colp = Ct + col * 256;
#pragma unroll
    for (int c = 0; c < 8; ++c) {
      const int chunk = hf * 8 + c;
      h8 vv = *(const h8*)(colp + ((chunk * 16) ^ cswz));
      *(h8*)(dst + c * 8) = vv;
    }
  } else {
    const int r0 = bm * 128 + wm * 64;
#pragma unroll
    for (int j = 0; j < 4; ++j) {
      int col = c0 + wn * 64 + j * 16 + rr;
      float bc = bias[col];
#pragma unroll
      for (int i = 0; i < 4; ++i) {
#pragma unroll
        for (int jj = 0; jj < 4; ++jj) {
          int row = r0 + i * 16 + (lane >> 4) * 4 + jj;
          float val = (acc[i][j][jj] + bc) * scale;
          int bb = row >> 11, s = row & (S_LEN - 1);
          int hh = col >> 6, dk = col & 63;
          ((half_t*)out)[(((size_t)(bb * NHEAD + hh)) * S_LEN + s) * HDK + dk] = (half_t)val;
        }
      }
    }
  }
#undef ASB
#undef BSB
}

// ---------------------------------------------------------------------------
// Output projection GEMM: 64x128 tile, grid 512 (2 blocks/CU, 8 waves/CU).
// Same BK=32 swizzle/dbuf staging math; acc[2][4]; f32 epilogue + bias.
__global__ __launch_bounds__(256) void gemm_o_kernel(
    const half_t* __restrict__ A, const half_t* __restrict__ W,
    const float* __restrict__ bias, float* __restrict__ out) {
  const int id = blockIdx.x;
  const int nid = (id & 7) * 64 + (id >> 3);  // 512 blocks, bijective
  const int bm = nid >> 3, bn = nid & 7;

  __shared__ char gsm[24576];  // A: 2x4KB @0 | B: 2x8KB @8192
#define OSB(buf) (gsm + (buf) * 4096)
#define OBB(buf) (gsm + 8192 + (buf) * 8192)

  const int tid = threadIdx.x, w = tid >> 6, lane = tid & 63;
  const int wm = w >> 1, wn = w & 1;
  const int crow = lane >> 2;
  const int ckb = ((lane & 3) * 16) ^ ((crow & 3) << 4);

  f32x4 acc[2][4] = {};

  const char* Ar = (const char*)A + (size_t)(bm * 64 + w * 16 + crow) * 2048 + ckb;
  const char* Wr0 = (const char*)W + (size_t)(bn * 128 + w * 16 + crow) * 2048 + ckb;
  const char* Wr1 = Wr0 + 64 * 2048;

  const int rr = lane & 15;
  const int kkB = (lane >> 4) * 16;
  const int kswz = (rr & 3) << 4;

#define OST(buf, ktB)                                      \
  do {                                                     \
    gload_lds16(Ar + (ktB), OSB(buf) + w * 1024);          \
    gload_lds16(Wr0 + (ktB), OBB(buf) + w * 1024);         \
    gload_lds16(Wr1 + (ktB), OBB(buf) + (w + 4) * 1024);   \
  } while (0)

  OST(0, 0);
  __syncthreads();

  int cur = 0;
  for (int ktB = 0; ktB < 2048; ktB += 64) {
    if (ktB + 64 < 2048) OST(cur ^ 1, ktB + 64);

    const char* AsB = OSB(cur);
    const char* BsB = OBB(cur);
    h8 af[2], bf[4];
#pragma unroll
    for (int i = 0; i < 2; ++i)
      af[i] = *(const h8*)(AsB + (wm * 32 + i * 16 + rr) * 64 + (kkB ^ kswz));
#pragma unroll
    for (int j = 0; j < 4; ++j)
      bf[j] = *(const h8*)(BsB + (wn * 64 + j * 16 + rr) * 64 + (kkB ^ kswz));
#pragma unroll
    for (int i = 0; i < 2; ++i)
#pragma unroll
      for (int j = 0; j < 4; ++j)
        acc[i][j] = __builtin_amdgcn_mfma_f32_16x16x32_f16(af[i], bf[j], acc[i][j], 0, 0, 0);

    __syncthreads();
    cur ^= 1;
  }
#undef OST
#undef OSB
#undef OBB

  const int r0 = bm * 64 + wm * 32;
  const int c0 = bn * 128 + wn * 64;
#pragma unroll
  for (int j = 0; j < 4; ++j) {
    int col = c0 + j * 16 + rr;
    float bc = bias[col];
#pragma unroll
    for (int i = 0; i < 2; ++i) {
#pragma unroll
      for (int jj = 0; jj < 4; ++jj) {
        int row = r0 + i * 16 + (lane >> 4) * 4 + jj;
        out[(size_t)row * DMODEL + col] = acc[i][j][jj] + bc;
      }
    }
  }
}

// ---------------------------------------------------------------------------
// Flash attention (R7-measured-best structure): 4-wave/256-thread blocks,
// grid 1024; 2 q-groups x 2 k-halves; K/V 32 KB LDS 2-buf via global_load_lds;
// no running max (masked scores -> 0 => p=1.0 == fp32 exp(1e-9)); additive
// k-half merge. R9 deltas: coalesced mbT mask loads + cvt_pkrtz P-pack.
__global__ __launch_bounds__(256, 4) void attn_kernel(
    const half_t* __restrict__ Qp, const half_t* __restrict__ Kp,
    const half_t* __restrict__ VTp, const unsigned int* __restrict__ mbT,
    half_t* __restrict__ AO) {
  __shared__ char smem[32768];  // K [2][8192] + V [2][8192]; merge reuse

  const int tid = threadIdx.x, w = tid >> 6, lane = tid & 63;
  const int qg = w >> 1, kh = w & 1;
  const int id = blockIdx.x;
  const int xcd = id & 7, rest = id >> 3;
  const int bh = (xcd << 2) | (rest >> 5);
  const int qt = rest & 31;
  const int b = bh >> 4, h = bh & 15;
  const int q32 = lane & 31, hi = lane >> 5;
  const int qbase = qt * 64 + qg * 32;
  const int qrowIdx = qbase + q32;
  const half_t* Qb = Qp + (size_t)bh * (S_LEN * HDK);
  const char* Kb = (const char*)(Kp + (size_t)bh * (S_LEN * HDK));
  const char* VTb = (const char*)(VTp + (size_t)bh * (S_LEN * HDK));

  char* Ks = smem;           // [2][8192]
  char* Vs = smem + 16384;   // [2][8192]
  const int srow = w * 16 + (lane >> 3);
  const int scb = (lane & 7) * 16;

  h8 qf[4];
#pragma unroll
  for (int s = 0; s < 4; ++s)
    qf[s] = *(const h8*)(Qb + (size_t)qrowIdx * HDK + s * 16 + hi * 8);

  f32x16 acc0 = {}, acc1 = {};
  float l_run = 0.f;

  unsigned int mw = mbT[(size_t)kh * S_LEN + qrowIdx];
#pragma unroll
  for (int p = 0; p < 2; ++p) {
    int r = srow + p * 8;
    gload_lds16(Kb + (size_t)r * 128 + (scb ^ ((r & 7) << 4)),
                Ks + (w * 16 + p * 8) * 128);
    gload_lds16(VTb + (size_t)r * (S_LEN * 2) + (scb ^ ((r & 7) << 4)),
                Vs + (w * 16 + p * 8) * 128);
  }
  __syncthreads();

  int cur = 0;
  for (int t = 0; t < 32; ++t) {
    const unsigned int mwc = mw >> (hi * 4);

    if (t < 31) {
      const int kvn = t + 1;
#pragma unroll
      for (int p = 0; p < 2; ++p) {
        int r = srow + p * 8;
        gload_lds16(Kb + (size_t)(kvn * 64 + r) * 128 + (scb ^ ((r & 7) << 4)),
                    Ks + (cur ^ 1) * 8192 + (w * 16 + p * 8) * 128);
        gload_lds16(VTb + (size_t)r * (S_LEN * 2) + kvn * 128 + (scb ^ ((r & 7) << 4)),
                    Vs + (cur ^ 1) * 8192 + (w * 16 + p * 8) * 128);
      }
      mw = mbT[(size_t)(kvn * 2 + kh) * S_LEN + qrowIdx];
    }

    const char* kb = Ks + cur * 8192;
    const char* vb = Vs + cur * 8192;
    f32x16 sc = {};
    __builtin_amdgcn_s_setprio(1);
#pragma unroll
    for (int s = 0; s < 4; ++s) {
      h8 kf = *(const h8*)(kb + swz(kh * 32 + q32, s * 32 + hi * 16));
      sc = __builtin_amdgcn_mfma_f32_32x32x16_f16(kf, qf[s], sc, 0, 0, 0);
    }
    __builtin_amdgcn_s_setprio(0);

    h8 vf00 = *(const h8*)(vb + swz(q32, kh * 64 + hi * 16));
    h8 vf01 = *(const h8*)(vb + swz(q32, kh * 64 + 32 + hi * 16));
    h8 vf10 = *(const h8*)(vb + swz(32 + q32, kh * 64 + hi * 16));
    h8 vf11 = *(const h8*)(vb + swz(32 + q32, kh * 64 + 32 + hi * 16));

#pragma unroll
    for (int rg = 0; rg < 16; ++rg) {
      const int bit = (rg & 3) + 8 * (rg >> 2);
      float p = fast_exp2(((mwc >> bit) & 1u) ? sc[rg] : 0.0f);
      sc[rg] = p;
      l_run += p;
    }

    h8 pb[2];
#pragma unroll
    for (int s = 0; s < 2; ++s) {
      const int rb = s * 8;
      union { fp16x2 hh; unsigned u; } c01, c23, c45, c67;
      c01.hh = __builtin_amdgcn_cvt_pkrtz(sc[rb + 0], sc[rb + 1]);
      c23.hh = __builtin_amdgcn_cvt_pkrtz(sc[rb + 2], sc[rb + 3]);
      c45.hh = __builtin_amdgcn_cvt_pkrtz(sc[rb + 4], sc[rb + 5]);
      c67.hh = __builtin_amdgcn_cvt_pkrtz(sc[rb + 6], sc[rb + 7]);
      auto rA = __builtin_amdgcn_permlane32_swap(c01.u, c45.u, false, false);
      auto rB = __builtin_amdgcn_permlane32_swap(c23.u, c67.u, false, false);
      union { unsigned int u[4]; h8 v_; } bw;
      bw.u[0] = rA[0]; bw.u[1] = rB[0]; bw.u[2] = rA[1]; bw.u[3] = rB[1];
      pb[s] = bw.v_;
    }

    __builtin_amdgcn_s_setprio(1);
    acc0 = __builtin_amdgcn_mfma_f32_32x32x16_f16(vf00, pb[0], acc0, 0, 0, 0);
    acc1 = __builtin_amdgcn_mfma_f32_32x32x16_f16(vf10, pb[0], acc1, 0, 0, 0);
    acc0 = __builtin_amdgcn_mfma_f32_32x32x16_f16(vf01, pb[1], acc0, 0, 0, 0);
    acc1 = __builtin_amdgcn_mfma_f32_32x32x16_f16(vf11, pb[1], acc1, 0, 0, 0);
    __builtin_amdgcn_s_setprio(0);

    __syncthreads();
    cur ^= 1;
  }

  float* my = (float*)smem + (qg * 64 + lane) * 33;
  if (kh) {
#pragma unroll
    for (int rg = 0; rg < 16; ++rg) { my[rg] = acc0[rg]; my[16 + rg] = acc1[rg]; }
    my[32] = l_run;
  }
  __syncthreads();
  if (!kh) {
#pragma unroll
    for (int rg = 0; rg < 16; ++rg) { acc0[rg] += my[rg]; acc1[rg] += my[16 + rg]; }
    l_run += my[32];
    l_run += __shfl_xor(l_run, 32);

    const float inv = 1.0f / l_run;
    half_t* aob = AO + (size_t)(b * S_LEN + qrowIdx) * DMODEL + h * HDK;
#pragma unroll
    for (int rq = 0; rq < 4; ++rq) {
      h4 s0, s1;
#pragma unroll
      for (int j = 0; j < 4; ++j) {
        s0[j] = (half_t)(acc0[rq * 4 + j] * inv);
        s1[j] = (half_t)(acc1[rq * 4 + j] * inv);
      }
      const int d0 = 8 * rq + 4 * hi;
      *(h4*)(aob + d0) = s0;
      *(h4*)(aob + 32 + d0) = s1;
    }
  }
}

// ---------------------------------------------------------------------------
extern "C" void kernel_launch(void* const* d_in, const int* in_sizes, int n_in,
                              void* d_out, int out_size, void* d_ws, size_t ws_size,
                              hipStream_t stream) {
  const float* q    = (const float*)d_in[0];
  const float* k    = (const float*)d_in[1];
  const float* v    = (const float*)d_in[2];
  const int*   mask = (const int*)d_in[3];
  const float* wq_w = (const float*)d_in[4];
  const float* wq_b = (const float*)d_in[5];
  const float* wk_w = (const float*)d_in[6];
  const float* wk_b = (const float*)d_in[7];
  const float* wv_w = (const float*)d_in[8];
  const float* wv_b = (const float*)d_in[9];
  const float* wo_w = (const float*)d_in[10];
  const float* wo_b = (const float*)d_in[11];
  float* out = (float*)d_out;

  char* ws = (char*)d_ws;
  const size_t MB = (size_t)1 << 20;
  half_t* Xq = (half_t*)(ws + 0 * MB);
  half_t* Xk = (half_t*)(ws + 8 * MB);
  half_t* Xv = (half_t*)(ws + 16 * MB);
  half_t* Wq = (half_t*)(ws + 24 * MB);
  half_t* Wk = (half_t*)(ws + 26 * MB);
  half_t* Wv = (half_t*)(ws + 28 * MB);
  half_t* Wo = (half_t*)(ws + 30 * MB);
  half_t* Qp = (half_t*)(ws + 32 * MB);
  half_t* Kp = (half_t*)(ws + 40 * MB);
  half_t* VT = (half_t*)(ws + 48 * MB);
  unsigned int* mbT = (unsigned int*)(ws + 56 * MB);
  half_t* AO = Xq;  // Xq dead after projections

  pre_kernel<<<32768, 256, 0, stream>>>(q, k, v, wq_w, wk_w, wv_w, wo_w, mask,
                                        Xq, Xk, Xv, Wq, Wk, Wv, Wo, mbT);
  gemm_kernel<<<768, 256, 0, stream>>>(
      Xq, Xk, Xv, Wq, Wk, Wv, wq_b, wk_b, wv_b, (void*)Qp, (void*)Kp, (void*)VT);
  attn_kernel<<<1024, 256, 0, stream>>>(Qp, Kp, VT, mbT, AO);
  gemm_o_kernel<<<512, 256, 0, stream>>>(AO, Wo, wo_b, out);

  (void)in_sizes; (void)n_in; (void)out_size; (void)ws_size;
}